// Round 14
// baseline (238.647 us; speedup 1.0000x reference)
//
#include <hip/hip_runtime.h>
#include <hip/hip_bf16.h>
#include <math.h>

#define H 128
#define H2 256
#define SLAB 96    // slots per row; P(Poisson(32) > 96) ~ 1e-18
#define LDA 136    // LDS row pitch (shorts) for K=128 tiles
#define LDA2 264   // LDS row pitch (shorts) for K=256 tiles
#define EPS 1e-5f

typedef __attribute__((ext_vector_type(8))) short s16x8;
typedef __attribute__((ext_vector_type(4))) float f32x4;

__device__ __forceinline__ unsigned short f2bf(float f) {
  unsigned u = __float_as_uint(f);
  unsigned r = (u + 0x7FFFu + ((u >> 16) & 1u)) >> 16;
  return (unsigned short)r;
}
__device__ __forceinline__ float bf2f(unsigned short s) {
  return __uint_as_float(((unsigned)s) << 16);
}

// ---------------------------------------------------------------------------
// Weight prep: transpose to [n][k] + bf16 (split hi/lo for Wq, Wk).
// ---------------------------------------------------------------------------
__global__ void wprep(const float* __restrict__ Wq, const float* __restrict__ Wk,
                      const float* __restrict__ Wv, const float* __restrict__ W1,
                      const float* __restrict__ W2,
                      short* qh, short* ql, short* kh, short* kl,
                      short* vh, short* w1h, short* w2h)
{
  int job = blockIdx.z;
  const float* src; short* dh; short* dl = nullptr; int Kd, Nn;
  if (job == 0)      { src = Wq; dh = qh;  dl = ql; Kd = 128; Nn = 128; }
  else if (job == 1) { src = Wk; dh = kh;  dl = kl; Kd = 128; Nn = 128; }
  else if (job == 2) { src = Wv; dh = vh;           Kd = 128; Nn = 128; }
  else if (job == 3) { src = W1; dh = w1h;          Kd = 128; Nn = 256; }
  else               { src = W2; dh = w2h;          Kd = 256; Nn = 128; }
  int t = blockIdx.x * 256 + threadIdx.x;
  if (t >= Kd * Nn) return;
  int n = t / Kd, k = t - n * Kd;
  float v = src[(size_t)k * Nn + n];
  unsigned short h = f2bf(v);
  dh[t] = (short)h;
  if (dl) dl[t] = (short)f2bf(v - bf2f(h));
}

// ---------------------------------------------------------------------------
// QKV via MFMA. 64-row M-tile, 256 threads. A split hi/lo staged once in LDS;
// B fragments direct from L2-hot [n][k] bf16 weights. SV goes to 8 banks.
// ---------------------------------------------------------------------------
__global__ __launch_bounds__(256) void qkv_mfma(
    const float* __restrict__ x,
    const short* __restrict__ Wqh, const short* __restrict__ Wql,
    const short* __restrict__ Wkh, const short* __restrict__ Wkl,
    const short* __restrict__ Wvh,
    const float* __restrict__ bq, const float* __restrict__ bk,
    const float* __restrict__ bv,
    float* __restrict__ Q, unsigned short* __restrict__ Kbf,
    unsigned short* __restrict__ Vbf, float* __restrict__ SVp)
{
  __shared__ __align__(16) short Ahi[64 * LDA];
  __shared__ __align__(16) short Alo[64 * LDA];
  int tid = threadIdx.x;
  int bm = blockIdx.x * 64;
  int wave = tid >> 6, lane = tid & 63;
  int quad = lane >> 4, l16 = lane & 15;
  int wn = wave * 32;

#pragma unroll
  for (int i = 0; i < 4; ++i) {
    int g = i * 256 + tid;
    int row = g >> 4, f = g & 15;
    const float4* xp = (const float4*)&x[(size_t)(bm + row) * H + f * 8];
    float4 v0 = xp[0], v1 = xp[1];
    float vv[8] = {v0.x, v0.y, v0.z, v0.w, v1.x, v1.y, v1.z, v1.w};
    s16x8 hv, lv;
#pragma unroll
    for (int j = 0; j < 8; ++j) {
      unsigned short hh = f2bf(vv[j]);
      hv[j] = (short)hh;
      lv[j] = (short)f2bf(vv[j] - bf2f(hh));
    }
    *(s16x8*)&Ahi[row * LDA + f * 8] = hv;
    *(s16x8*)&Alo[row * LDA + f * 8] = lv;
  }
  __syncthreads();

  for (int ph = 0; ph < 3; ++ph) {
    const short* Bh = (ph == 0) ? Wqh : (ph == 1) ? Wkh : Wvh;
    const short* Bl = (ph == 0) ? Wql : (ph == 1) ? Wkl : nullptr;

    s16x8 bh[2][4], bl2[2][4];
#pragma unroll
    for (int nt = 0; nt < 2; ++nt)
#pragma unroll
      for (int ks = 0; ks < 4; ++ks)
        bh[nt][ks] = *(const s16x8*)&Bh[(size_t)(wn + nt * 16 + l16) * H + ks * 32 + quad * 8];
    if (Bl) {
#pragma unroll
      for (int nt = 0; nt < 2; ++nt)
#pragma unroll
        for (int ks = 0; ks < 4; ++ks)
          bl2[nt][ks] = *(const s16x8*)&Bl[(size_t)(wn + nt * 16 + l16) * H + ks * 32 + quad * 8];
    }

    f32x4 acc[4][2];
#pragma unroll
    for (int mt = 0; mt < 4; ++mt)
#pragma unroll
      for (int nt = 0; nt < 2; ++nt) acc[mt][nt] = (f32x4){0.f, 0.f, 0.f, 0.f};

#pragma unroll
    for (int ks = 0; ks < 4; ++ks) {
      int kof = ks * 32 + quad * 8;
      s16x8 ah[4], al[4];
#pragma unroll
      for (int mt = 0; mt < 4; ++mt) {
        ah[mt] = *(s16x8*)&Ahi[(mt * 16 + l16) * LDA + kof];
        al[mt] = *(s16x8*)&Alo[(mt * 16 + l16) * LDA + kof];
      }
#pragma unroll
      for (int mt = 0; mt < 4; ++mt)
#pragma unroll
        for (int nt = 0; nt < 2; ++nt) {
          acc[mt][nt] = __builtin_amdgcn_mfma_f32_16x16x32_bf16(ah[mt], bh[nt][ks], acc[mt][nt], 0, 0, 0);
          if (ph < 2) {
            acc[mt][nt] = __builtin_amdgcn_mfma_f32_16x16x32_bf16(ah[mt], bl2[nt][ks], acc[mt][nt], 0, 0, 0);
            acc[mt][nt] = __builtin_amdgcn_mfma_f32_16x16x32_bf16(al[mt], bh[nt][ks], acc[mt][nt], 0, 0, 0);
          }
        }
    }

    if (ph == 0) {
#pragma unroll
      for (int nt = 0; nt < 2; ++nt) {
        int col = wn + nt * 16 + l16;
        float bb = bq[col];
#pragma unroll
        for (int mt = 0; mt < 4; ++mt)
#pragma unroll
          for (int r = 0; r < 4; ++r) {
            int row = bm + mt * 16 + quad * 4 + r;
            Q[(size_t)row * H + col] = acc[mt][nt][r] + bb;
          }
      }
    } else if (ph == 1) {
#pragma unroll
      for (int nt = 0; nt < 2; ++nt) {
        int col = wn + nt * 16 + l16;
        float bb = bk[col];
#pragma unroll
        for (int mt = 0; mt < 4; ++mt)
#pragma unroll
          for (int r = 0; r < 4; ++r) {
            int row = bm + mt * 16 + quad * 4 + r;
            Kbf[(size_t)row * H + col] = f2bf(acc[mt][nt][r] + bb);
          }
      }
    } else {
      int bank = blockIdx.x & 7;
#pragma unroll
      for (int nt = 0; nt < 2; ++nt) {
        int col = wn + nt * 16 + l16;
        float bb = bv[col];
        float ps = 0.f;
#pragma unroll
        for (int mt = 0; mt < 4; ++mt)
#pragma unroll
          for (int r = 0; r < 4; ++r) {
            int row = bm + mt * 16 + quad * 4 + r;
            float v = acc[mt][nt][r] + bb;
            Vbf[(size_t)row * H + col] = f2bf(v);
            ps += v;
          }
        ps += __shfl_xor(ps, 16);
        ps += __shfl_xor(ps, 32);
        if (quad == 0) atomicAdd(&SVp[bank * H + col], ps);
      }
    }
  }
}

// ---------------------------------------------------------------------------
// XCD-grouped edge scatter (lean footprint: no LDS, low VGPR).
// ---------------------------------------------------------------------------
__global__ void ebfill(const float* __restrict__ ea,
                       const float* __restrict__ We,
                       const float* __restrict__ be,
                       const int* __restrict__ ei,
                       int* __restrict__ cnt,
                       int2* __restrict__ slabDE, int E, int N)
{
  int grp = blockIdx.x & 7;
  int blk = blockIdx.x >> 3;
  int lo = grp * (N >> 3), hi = lo + (N >> 3);
  int per = E >> 8;                 // edges per window (2048)
  int base = blk * per;
  float4 w0 = *(const float4*)&We[0], w1 = *(const float4*)&We[4];
  float4 w2 = *(const float4*)&We[8], w3 = *(const float4*)&We[12];
  float bias = be[0];
  for (int i = 0; i < per; i += 256) {
    int e = base + i + threadIdx.x;
    if (e >= E) continue;
    int src = ei[e];
    if (src < lo || src >= hi) continue;
    int dst = ei[E + e];
    const float4* p = (const float4*)&ea[(size_t)e * 16];
    float4 a0 = p[0], a1 = p[1], a2 = p[2], a3 = p[3];
    float s = a0.x * w0.x + a0.y * w0.y + a0.z * w0.z + a0.w * w0.w
            + a1.x * w1.x + a1.y * w1.y + a1.z * w1.z + a1.w * w1.w
            + a2.x * w2.x + a2.y * w2.y + a2.z * w2.z + a2.w * w2.w
            + a3.x * w3.x + a3.y * w3.y + a3.z * w3.z + a3.w * w3.w;
    s += bias;
    int pos = atomicAdd(&cnt[src], 1);
    if (pos < SLAB) {
      int2 rec; rec.x = dst; rec.y = __float_as_int(s);
      slabDE[src * SLAB + pos] = rec;
    }
  }
}

// ---------------------------------------------------------------------------
// Fused attention: score (4 edges in flight per 8-lane subteam) + dedup +
// sparse softmax vs dense-zero background + P@V + residual + banked BN1 stats.
// 8 rows/block, one 32-lane team per row.
// ---------------------------------------------------------------------------
__global__ __launch_bounds__(256) void attn_fused(
    const float* __restrict__ x, const float* __restrict__ Q,
    const unsigned short* __restrict__ Kbf, const unsigned short* __restrict__ Vbf,
    const float* __restrict__ SVp, const int* __restrict__ cnt,
    const int2* __restrict__ slabDE,
    float* __restrict__ h1, float* __restrict__ sum1p, float* __restrict__ sq1p,
    int N)
{
  __shared__ float sv[8][SLAB];
  __shared__ int sd[8][SLAB];
  __shared__ unsigned char sown[8][SLAB];
  __shared__ float csum[H], csq[H], svf[H];
  int tid = threadIdx.x;
  int team = tid >> 5, lane = tid & 31;
  int i = blockIdx.x * 8 + team;
  int k = cnt[i]; if (k > SLAB) k = SLAB;
  int base = i * SLAB;

  if (tid < H) {
    csum[tid] = 0.f; csq[tid] = 0.f;
    float s = 0.f;
#pragma unroll
    for (int b = 0; b < 8; ++b) s += SVp[b * H + tid];
    svf[tid] = s;
  }

  // stage slab: sd = dst, sv = edge-bias seed
  for (int p = lane; p < k; p += 32) {
    int2 de = slabDE[base + p];
    sd[team][p] = de.x;
    sv[team][p] = __int_as_float(de.y);
  }
  __syncthreads();   // covers csum/svf init + slab visibility

  // ---- scoring: 4 subteams of 8 lanes, 4 edges in flight per subteam ----
  int sub8 = lane & 7, sub4 = lane >> 3;
  const float4* q4 = (const float4*)(Q + (size_t)i * H);
  float4 qa0 = q4[2 * sub8], qa1 = q4[2 * sub8 + 1];
  float4 qb0 = q4[16 + 2 * sub8], qb1 = q4[17 + 2 * sub8];
  for (int p0 = sub4 * 4; p0 < k; p0 += 16) {
    int d[4]; bool has[4];
#pragma unroll
    for (int u = 0; u < 4; ++u) {
      has[u] = (p0 + u < k);
      d[u] = sd[team][has[u] ? (p0 + u) : p0];
    }
    s16x8 ka[4], kb[4];
#pragma unroll
    for (int u = 0; u < 4; ++u) {
      const s16x8* kp = (const s16x8*)(Kbf + (size_t)d[u] * H);
      ka[u] = kp[sub8];
      kb[u] = kp[8 + sub8];
    }
    float dp[4];
#pragma unroll
    for (int u = 0; u < 4; ++u) {
      dp[u] = qa0.x * bf2f((unsigned short)ka[u][0]) + qa0.y * bf2f((unsigned short)ka[u][1])
            + qa0.z * bf2f((unsigned short)ka[u][2]) + qa0.w * bf2f((unsigned short)ka[u][3])
            + qa1.x * bf2f((unsigned short)ka[u][4]) + qa1.y * bf2f((unsigned short)ka[u][5])
            + qa1.z * bf2f((unsigned short)ka[u][6]) + qa1.w * bf2f((unsigned short)ka[u][7])
            + qb0.x * bf2f((unsigned short)kb[u][0]) + qb0.y * bf2f((unsigned short)kb[u][1])
            + qb0.z * bf2f((unsigned short)kb[u][2]) + qb0.w * bf2f((unsigned short)kb[u][3])
            + qb1.x * bf2f((unsigned short)kb[u][4]) + qb1.y * bf2f((unsigned short)kb[u][5])
            + qb1.z * bf2f((unsigned short)kb[u][6]) + qb1.w * bf2f((unsigned short)kb[u][7]);
    }
#pragma unroll
    for (int u = 0; u < 4; ++u) {
      dp[u] += __shfl_xor(dp[u], 1);
      dp[u] += __shfl_xor(dp[u], 2);
      dp[u] += __shfl_xor(dp[u], 4);
    }
    if (sub8 == 0) {
#pragma unroll
      for (int u = 0; u < 4; ++u)
        if (has[u]) {
          float s0 = dp[u] + sv[team][p0 + u];
          sv[team][p0 + u] = (s0 >= 0.f) ? s0 : 0.01f * s0;
        }
    }
  }

  // ---- dedup: first slot with same dst owns; sum dup scores pre-exp ----
  for (int p = lane; p < k; p += 32) {
    int d = sd[team][p], o = p;
    for (int q = 0; q < p; ++q)
      if (sd[team][q] == d) { o = q; break; }
    sown[team][p] = (unsigned char)o;
  }
  for (int p = lane; p < k; p += 32)
    if (sown[team][p] != (unsigned char)p)
      atomicAdd(&sv[team][sown[team][p]], sv[team][p]);

  // ---- softmax (vs dense-zero background) ----
  float m = 0.f;
  for (int p = lane; p < k; p += 32)
    if (sown[team][p] == (unsigned char)p) m = fmaxf(m, sv[team][p]);
#pragma unroll
  for (int mask = 16; mask; mask >>= 1) m = fmaxf(m, __shfl_xor(m, mask));
  float em = expf(-m);

  float zl = 0.f;
  for (int p = lane; p < k; p += 32) {
    float cf = 0.f;
    if (sown[team][p] == (unsigned char)p) cf = expf(sv[team][p] - m) - em;
    sv[team][p] = cf;
    zl += cf;
  }
#pragma unroll
  for (int mask = 16; mask; mask >>= 1) zl += __shfl_xor(zl, mask);
  float Zi = 1.f / ((float)N * em + zl);

  // ---- P @ V (bf16 V gathers, 8 in flight) + residual ----
  const ushort4* V4 = (const ushort4*)Vbf;
  float4 s4 = *(const float4*)&svf[lane * 4];
  float ax = em * s4.x, ay = em * s4.y, az = em * s4.z, aw = em * s4.w;
  int c = 0;
  for (; c + 8 <= k; c += 8) {
    float cf[8]; int dd[8]; ushort4 vv[8];
#pragma unroll
    for (int u = 0; u < 8; ++u) { cf[u] = sv[team][c + u]; dd[u] = sd[team][c + u]; }
#pragma unroll
    for (int u = 0; u < 8; ++u) vv[u] = V4[(size_t)dd[u] * 32 + lane];
#pragma unroll
    for (int u = 0; u < 8; ++u) {
      ax += cf[u] * bf2f(vv[u].x);
      ay += cf[u] * bf2f(vv[u].y);
      az += cf[u] * bf2f(vv[u].z);
      aw += cf[u] * bf2f(vv[u].w);
    }
  }
  for (; c < k; ++c) {
    float cf = sv[team][c];
    ushort4 v0 = V4[(size_t)sd[team][c] * 32 + lane];
    ax += cf * bf2f(v0.x); ay += cf * bf2f(v0.y);
    az += cf * bf2f(v0.z); aw += cf * bf2f(v0.w);
  }
  float4 xx = *(const float4*)&x[(size_t)i * H + lane * 4];
  float4 out;
  out.x = xx.x + ax * Zi; out.y = xx.y + ay * Zi;
  out.z = xx.z + az * Zi; out.w = xx.w + aw * Zi;
  *(float4*)&h1[(size_t)i * H + lane * 4] = out;

  // ---- banked BN1 stats ----
  int c0 = lane * 4;
  atomicAdd(&csum[c0 + 0], out.x); atomicAdd(&csq[c0 + 0], out.x * out.x);
  atomicAdd(&csum[c0 + 1], out.y); atomicAdd(&csq[c0 + 1], out.y * out.y);
  atomicAdd(&csum[c0 + 2], out.z); atomicAdd(&csq[c0 + 2], out.z * out.z);
  atomicAdd(&csum[c0 + 3], out.w); atomicAdd(&csq[c0 + 3], out.w * out.w);
  __syncthreads();
  if (tid < H) {
    int bank = blockIdx.x & 15;
    atomicAdd(&sum1p[bank * H + tid], csum[tid]);
    atomicAdd(&sq1p[bank * H + tid], csq[tid]);
  }
}

// ---------------------------------------------------------------------------
// Fused FFN (banked-stats): folds sum1p/sq1p in prologue; t1 tile in LDS only;
// writes BN2 partial sums to 16 banks.
// ---------------------------------------------------------------------------
__global__ __launch_bounds__(256) void ffn_fused(
    const float* __restrict__ h1, const short* __restrict__ W1h,
    const float* __restrict__ b1, const short* __restrict__ W2h,
    const float* __restrict__ b2,
    const float* __restrict__ sum1p, const float* __restrict__ sq1p,
    const float* __restrict__ g1, const float* __restrict__ bb1,
    float* __restrict__ h2, float* __restrict__ sum2p, float* __restrict__ sq2p,
    float invN)
{
  __shared__ __align__(16) short As[32 * LDA];
  __shared__ __align__(16) short Ts[32 * LDA2];
  __shared__ float aF[H], bF[H];
  int tid = threadIdx.x;
  int bm = blockIdx.x * 32;
  int wave = tid >> 6, lane = tid & 63;
  int quad = lane >> 4, l16 = lane & 15;

  if (tid < H) {
    float s = 0.f, q = 0.f;
#pragma unroll
    for (int b = 0; b < 16; ++b) { s += sum1p[b * H + tid]; q += sq1p[b * H + tid]; }
    float mu = s * invN;
    float var = q * invN - mu * mu;
    float rs = rsqrtf(var + EPS);
    float a = g1[tid] * rs;
    aF[tid] = a;
    bF[tid] = bb1[tid] - a * mu;
  }
  __syncthreads();

  int f = tid & 15;
#pragma unroll
  for (int i = 0; i < 2; ++i) {
    int g = i * 256 + tid;
    int row = g >> 4;
    const float4* xp = (const float4*)&h1[(size_t)(bm + row) * H + f * 8];
    float4 v0 = xp[0], v1 = xp[1];
    float vv[8] = {v0.x, v0.y, v0.z, v0.w, v1.x, v1.y, v1.z, v1.w};
    s16x8 hv;
#pragma unroll
    for (int j = 0; j < 8; ++j) {
      int c = f * 8 + j;
      hv[j] = (short)f2bf(aF[c] * vv[j] + bF[c]);
    }
    *(s16x8*)&As[row * LDA + f * 8] = hv;
  }

  int wn1 = wave * 64;
  s16x8 b1f[4][4];
#pragma unroll
  for (int nt = 0; nt < 4; ++nt)
#pragma unroll
    for (int ks = 0; ks < 4; ++ks)
      b1f[nt][ks] = *(const s16x8*)&W1h[(size_t)(wn1 + nt * 16 + l16) * H + ks * 32 + quad * 8];
  __syncthreads();

  f32x4 acc1[2][4];
#pragma unroll
  for (int mt = 0; mt < 2; ++mt)
#pragma unroll
    for (int nt = 0; nt < 4; ++nt) acc1[mt][nt] = (f32x4){0.f, 0.f, 0.f, 0.f};

#pragma unroll
  for (int ks = 0; ks < 4; ++ks) {
    int kof = ks * 32 + quad * 8;
    s16x8 ah[2];
#pragma unroll
    for (int mt = 0; mt < 2; ++mt) ah[mt] = *(s16x8*)&As[(mt * 16 + l16) * LDA + kof];
#pragma unroll
    for (int mt = 0; mt < 2; ++mt)
#pragma unroll
      for (int nt = 0; nt < 4; ++nt)
        acc1[mt][nt] = __builtin_amdgcn_mfma_f32_16x16x32_bf16(ah[mt], b1f[nt][ks], acc1[mt][nt], 0, 0, 0);
  }

#pragma unroll
  for (int nt = 0; nt < 4; ++nt) {
    int col = wn1 + nt * 16 + l16;
    float bb = b1[col];
#pragma unroll
    for (int mt = 0; mt < 2; ++mt)
#pragma unroll
      for (int r = 0; r < 4; ++r) {
        int row = mt * 16 + quad * 4 + r;
        float v = acc1[mt][nt][r] + bb;
        v = v > 0.f ? v : 0.f;
        Ts[row * LDA2 + col] = (short)f2bf(v);
      }
  }

  int wn2 = wave * 32;
  s16x8 b2f[2][8];
#pragma unroll
  for (int nt = 0; nt < 2; ++nt)
#pragma unroll
    for (int ks = 0; ks < 8; ++ks)
      b2f[nt][ks] = *(const s16x8*)&W2h[(size_t)(wn2 + nt * 16 + l16) * H2 + ks * 32 + quad * 8];
  __syncthreads();

  f32x4 acc2[2][2];
#pragma unroll
  for (int mt = 0; mt < 2; ++mt)
#pragma unroll
    for (int nt = 0; nt < 2; ++nt) acc2[mt][nt] = (f32x4){0.f, 0.f, 0.f, 0.f};

#pragma unroll
  for (int ks = 0; ks < 8; ++ks) {
    int kof = ks * 32 + quad * 8;
    s16x8 ah[2];
#pragma unroll
    for (int mt = 0; mt < 2; ++mt) ah[mt] = *(s16x8*)&Ts[(mt * 16 + l16) * LDA2 + kof];
#pragma unroll
    for (int mt = 0; mt < 2; ++mt)
#pragma unroll
      for (int nt = 0; nt < 2; ++nt)
        acc2[mt][nt] = __builtin_amdgcn_mfma_f32_16x16x32_bf16(ah[mt], b2f[nt][ks], acc2[mt][nt], 0, 0, 0);
  }

  int bank = blockIdx.x & 15;
#pragma unroll
  for (int nt = 0; nt < 2; ++nt) {
    int col = wn2 + nt * 16 + l16;
    float ra = aF[col], rb = bF[col];
    float bb = b2[col];
    float ps = 0.f, pq = 0.f;
#pragma unroll
    for (int mt = 0; mt < 2; ++mt)
#pragma unroll
      for (int r = 0; r < 4; ++r) {
        int row = bm + mt * 16 + quad * 4 + r;
        float rr = ra * h1[(size_t)row * H + col] + rb;
        float v = acc2[mt][nt][r] + bb + rr;
        h2[(size_t)row * H + col] = v;
        ps += v; pq += v * v;
      }
    ps += __shfl_xor(ps, 16); ps += __shfl_xor(ps, 32);
    pq += __shfl_xor(pq, 16); pq += __shfl_xor(pq, 32);
    if (quad == 0) {
      atomicAdd(&sum2p[bank * H + col], ps);
      atomicAdd(&sq2p[bank * H + col], pq);
    }
  }
}

// BN2: fold 16 banks -> affine in LDS, then vectorized apply.
__global__ __launch_bounds__(256) void bn_apply(
    const float* __restrict__ X,
    const float* __restrict__ sum2p, const float* __restrict__ sq2p,
    const float* __restrict__ g2, const float* __restrict__ bb2,
    float* __restrict__ Y, size_t n4, float invN)
{
  __shared__ float A2s[H], B2s[H];
  int tid = threadIdx.x;
  if (tid < H) {
    float s = 0.f, q = 0.f;
#pragma unroll
    for (int b = 0; b < 16; ++b) { s += sum2p[b * H + tid]; q += sq2p[b * H + tid]; }
    float mu = s * invN;
    float var = q * invN - mu * mu;
    float rs = rsqrtf(var + EPS);
    float a = g2[tid] * rs;
    A2s[tid] = a;
    B2s[tid] = bb2[tid] - a * mu;
  }
  __syncthreads();
  size_t i = (size_t)blockIdx.x * blockDim.x + tid;
  if (i >= n4) return;
  float4 v = ((const float4*)X)[i];
  int c = (int)((i * 4) & (H - 1));
  float4 a = *(const float4*)&A2s[c];
  float4 b = *(const float4*)&B2s[c];
  v.x = a.x * v.x + b.x; v.y = a.y * v.y + b.y;
  v.z = a.z * v.z + b.z; v.w = a.w * v.w + b.w;
  ((float4*)Y)[i] = v;
}

// ---------------------------------------------------------------------------
extern "C" void kernel_launch(void* const* d_in, const int* in_sizes, int n_in,
                              void* d_out, int out_size, void* d_ws, size_t ws_size,
                              hipStream_t stream)
{
  const float* x  = (const float*)d_in[0];
  const int*   ei = (const int*)d_in[1];
  const float* ea = (const float*)d_in[2];
  const float* Wq = (const float*)d_in[3];
  const float* bq = (const float*)d_in[4];
  const float* Wk = (const float*)d_in[5];
  const float* bk = (const float*)d_in[6];
  const float* Wv = (const float*)d_in[7];
  const float* bv = (const float*)d_in[8];
  const float* We = (const float*)d_in[9];
  const float* be = (const float*)d_in[10];
  const float* g1 = (const float*)d_in[11];
  const float* bb1 = (const float*)d_in[12];
  const float* W1 = (const float*)d_in[13];
  const float* b1 = (const float*)d_in[14];
  const float* W2 = (const float*)d_in[15];
  const float* b2 = (const float*)d_in[16];
  const float* g2 = (const float*)d_in[17];
  const float* bb2 = (const float*)d_in[18];

  int N = in_sizes[0] / H;      // 16384
  int E = in_sizes[2] / 16;     // 524288
  size_t NH = (size_t)N * H;
  float invN = 1.0f / (float)N;

  float* Q   = (float*)d_ws;                         // 8 MB
  float* KmSlot = Q + NH;                            // 8 MB (Kbf + later h2)
  float* h1  = KmSlot + NH;                          // 8 MB
  unsigned short* Vbf = (unsigned short*)(h1 + NH);  // 4 MB
  int2*  slabDE = (int2*)(Vbf + NH);                 // 12 MB
  float* sAslab = (float*)(slabDE + (size_t)N * SLAB);  // 6 MB (unused now)
  int*   cnt    = (int*)(sAslab + (size_t)N * SLAB);
  float* stats  = (float*)(cnt + N);
  float* SVp   = stats;
  float* sum1p = stats + 8 * H;
  float* sq1p  = sum1p + 16 * H;
  float* sum2p = sq1p + 16 * H;
  float* sq2p  = sum2p + 16 * H;
  float* statsEnd = sq2p + 16 * H;      // 72*H floats total
  short* wbuf = (short*)statsEnd;
  short* Wqh = wbuf;
  short* Wql = Wqh + 16384;
  short* Wkh = Wql + 16384;
  short* Wkl = Wkh + 16384;
  short* Wvh = Wkl + 16384;
  short* W1h = Wvh + 16384;
  short* W2h = W1h + 32768;
  unsigned short* Kbf = (unsigned short*)KmSlot;  // 4 MB, dead after attn_fused
  float* h2 = KmSlot;                             // alias (Kbf dead after attn)

  hipMemsetAsync(cnt, 0, (size_t)N * sizeof(int), stream);
  hipMemsetAsync(stats, 0, (size_t)72 * H * sizeof(float), stream);

  wprep<<<dim3(128, 1, 5), 256, 0, stream>>>(Wq, Wk, Wv, W1, W2,
      Wqh, Wql, Wkh, Wkl, Wvh, W1h, W2h);

  qkv_mfma<<<dim3(N / 64), 256, 0, stream>>>(
      x, Wqh, Wql, Wkh, Wkl, Wvh, bq, bk, bv, Q, Kbf, Vbf, SVp);

  ebfill<<<dim3(2048), 256, 0, stream>>>(ea, We, be, ei, cnt, slabDE, E, N);

  attn_fused<<<dim3(N / 8), 256, 0, stream>>>(x, Q, Kbf, Vbf, SVp, cnt, slabDE,
                                              h1, sum1p, sq1p, N);

  ffn_fused<<<dim3(N / 32), 256, 0, stream>>>(h1, W1h, b1, W2h, b2,
      sum1p, sq1p, g1, bb1, h2, sum2p, sq2p, invN);

  bn_apply<<<dim3((int)((NH / 4 + 255) / 256)), 256, 0, stream>>>(
      h2, sum2p, sq2p, g2, bb2, (float*)d_out, NH / 4, invN);
}

// Round 15
// 229.862 us; speedup vs baseline: 1.0382x; 1.0382x over previous
//
#include <hip/hip_runtime.h>
#include <hip/hip_bf16.h>
#include <math.h>

#define H 128
#define H2 256
#define SLAB 96    // slots per row; P(Poisson(32) > 96) ~ 1e-18
#define LDA 136    // LDS row pitch (shorts) for K=128 tiles
#define LDA2 264   // LDS row pitch (shorts) for K=256 tiles
#define EPS 1e-5f

typedef __attribute__((ext_vector_type(8))) short s16x8;
typedef __attribute__((ext_vector_type(4))) float f32x4;

__device__ __forceinline__ unsigned short f2bf(float f) {
  unsigned u = __float_as_uint(f);
  unsigned r = (u + 0x7FFFu + ((u >> 16) & 1u)) >> 16;
  return (unsigned short)r;
}
__device__ __forceinline__ float bf2f(unsigned short s) {
  return __uint_as_float(((unsigned)s) << 16);
}

// ---------------------------------------------------------------------------
// Weight prep: transpose to [n][k] + bf16 (split hi/lo for Wq, Wk).
// ---------------------------------------------------------------------------
__global__ void wprep(const float* __restrict__ Wq, const float* __restrict__ Wk,
                      const float* __restrict__ Wv, const float* __restrict__ W1,
                      const float* __restrict__ W2,
                      short* qh, short* ql, short* kh, short* kl,
                      short* vh, short* w1h, short* w2h)
{
  int job = blockIdx.z;
  const float* src; short* dh; short* dl = nullptr; int Kd, Nn;
  if (job == 0)      { src = Wq; dh = qh;  dl = ql; Kd = 128; Nn = 128; }
  else if (job == 1) { src = Wk; dh = kh;  dl = kl; Kd = 128; Nn = 128; }
  else if (job == 2) { src = Wv; dh = vh;           Kd = 128; Nn = 128; }
  else if (job == 3) { src = W1; dh = w1h;          Kd = 128; Nn = 256; }
  else               { src = W2; dh = w2h;          Kd = 256; Nn = 128; }
  int t = blockIdx.x * 256 + threadIdx.x;
  if (t >= Kd * Nn) return;
  int n = t / Kd, k = t - n * Kd;
  float v = src[(size_t)k * Nn + n];
  unsigned short h = f2bf(v);
  dh[t] = (short)h;
  if (dl) dl[t] = (short)f2bf(v - bf2f(h));
}

// ---------------------------------------------------------------------------
// QKV via MFMA. 64-row M-tile, 256 threads. A split hi/lo staged once in LDS;
// B fragments direct from L2-hot [n][k] bf16 weights. SV goes to 8 banks.
// ---------------------------------------------------------------------------
__global__ __launch_bounds__(256) void qkv_mfma(
    const float* __restrict__ x,
    const short* __restrict__ Wqh, const short* __restrict__ Wql,
    const short* __restrict__ Wkh, const short* __restrict__ Wkl,
    const short* __restrict__ Wvh,
    const float* __restrict__ bq, const float* __restrict__ bk,
    const float* __restrict__ bv,
    float* __restrict__ Q, unsigned short* __restrict__ Kbf,
    unsigned short* __restrict__ Vbf, float* __restrict__ SVp)
{
  __shared__ __align__(16) short Ahi[64 * LDA];
  __shared__ __align__(16) short Alo[64 * LDA];
  int tid = threadIdx.x;
  int bm = blockIdx.x * 64;
  int wave = tid >> 6, lane = tid & 63;
  int quad = lane >> 4, l16 = lane & 15;
  int wn = wave * 32;

#pragma unroll
  for (int i = 0; i < 4; ++i) {
    int g = i * 256 + tid;
    int row = g >> 4, f = g & 15;
    const float4* xp = (const float4*)&x[(size_t)(bm + row) * H + f * 8];
    float4 v0 = xp[0], v1 = xp[1];
    float vv[8] = {v0.x, v0.y, v0.z, v0.w, v1.x, v1.y, v1.z, v1.w};
    s16x8 hv, lv;
#pragma unroll
    for (int j = 0; j < 8; ++j) {
      unsigned short hh = f2bf(vv[j]);
      hv[j] = (short)hh;
      lv[j] = (short)f2bf(vv[j] - bf2f(hh));
    }
    *(s16x8*)&Ahi[row * LDA + f * 8] = hv;
    *(s16x8*)&Alo[row * LDA + f * 8] = lv;
  }
  __syncthreads();

  for (int ph = 0; ph < 3; ++ph) {
    const short* Bh = (ph == 0) ? Wqh : (ph == 1) ? Wkh : Wvh;
    const short* Bl = (ph == 0) ? Wql : (ph == 1) ? Wkl : nullptr;

    s16x8 bh[2][4], bl2[2][4];
#pragma unroll
    for (int nt = 0; nt < 2; ++nt)
#pragma unroll
      for (int ks = 0; ks < 4; ++ks)
        bh[nt][ks] = *(const s16x8*)&Bh[(size_t)(wn + nt * 16 + l16) * H + ks * 32 + quad * 8];
    if (Bl) {
#pragma unroll
      for (int nt = 0; nt < 2; ++nt)
#pragma unroll
        for (int ks = 0; ks < 4; ++ks)
          bl2[nt][ks] = *(const s16x8*)&Bl[(size_t)(wn + nt * 16 + l16) * H + ks * 32 + quad * 8];
    }

    f32x4 acc[4][2];
#pragma unroll
    for (int mt = 0; mt < 4; ++mt)
#pragma unroll
      for (int nt = 0; nt < 2; ++nt) acc[mt][nt] = (f32x4){0.f, 0.f, 0.f, 0.f};

#pragma unroll
    for (int ks = 0; ks < 4; ++ks) {
      int kof = ks * 32 + quad * 8;
      s16x8 ah[4], al[4];
#pragma unroll
      for (int mt = 0; mt < 4; ++mt) {
        ah[mt] = *(s16x8*)&Ahi[(mt * 16 + l16) * LDA + kof];
        al[mt] = *(s16x8*)&Alo[(mt * 16 + l16) * LDA + kof];
      }
#pragma unroll
      for (int mt = 0; mt < 4; ++mt)
#pragma unroll
        for (int nt = 0; nt < 2; ++nt) {
          acc[mt][nt] = __builtin_amdgcn_mfma_f32_16x16x32_bf16(ah[mt], bh[nt][ks], acc[mt][nt], 0, 0, 0);
          if (ph < 2) {
            acc[mt][nt] = __builtin_amdgcn_mfma_f32_16x16x32_bf16(ah[mt], bl2[nt][ks], acc[mt][nt], 0, 0, 0);
            acc[mt][nt] = __builtin_amdgcn_mfma_f32_16x16x32_bf16(al[mt], bh[nt][ks], acc[mt][nt], 0, 0, 0);
          }
        }
    }

    if (ph == 0) {
#pragma unroll
      for (int nt = 0; nt < 2; ++nt) {
        int col = wn + nt * 16 + l16;
        float bb = bq[col];
#pragma unroll
        for (int mt = 0; mt < 4; ++mt)
#pragma unroll
          for (int r = 0; r < 4; ++r) {
            int row = bm + mt * 16 + quad * 4 + r;
            Q[(size_t)row * H + col] = acc[mt][nt][r] + bb;
          }
      }
    } else if (ph == 1) {
#pragma unroll
      for (int nt = 0; nt < 2; ++nt) {
        int col = wn + nt * 16 + l16;
        float bb = bk[col];
#pragma unroll
        for (int mt = 0; mt < 4; ++mt)
#pragma unroll
          for (int r = 0; r < 4; ++r) {
            int row = bm + mt * 16 + quad * 4 + r;
            Kbf[(size_t)row * H + col] = f2bf(acc[mt][nt][r] + bb);
          }
      }
    } else {
      int bank = blockIdx.x & 7;
#pragma unroll
      for (int nt = 0; nt < 2; ++nt) {
        int col = wn + nt * 16 + l16;
        float bb = bv[col];
        float ps = 0.f;
#pragma unroll
        for (int mt = 0; mt < 4; ++mt)
#pragma unroll
          for (int r = 0; r < 4; ++r) {
            int row = bm + mt * 16 + quad * 4 + r;
            float v = acc[mt][nt][r] + bb;
            Vbf[(size_t)row * H + col] = f2bf(v);
            ps += v;
          }
        ps += __shfl_xor(ps, 16);
        ps += __shfl_xor(ps, 32);
        if (quad == 0) atomicAdd(&SVp[bank * H + col], ps);
      }
    }
  }
}

// ---------------------------------------------------------------------------
// Edge bias, coalesced BW-bound pass: Eb = ea @ We + be.
// ---------------------------------------------------------------------------
__global__ void eb_compute(const float* __restrict__ ea,
                           const float* __restrict__ We,
                           const float* __restrict__ be,
                           float* __restrict__ Eb, int E)
{
  int e = blockIdx.x * blockDim.x + threadIdx.x;
  if (e >= E) return;
  const float4* p = (const float4*)&ea[(size_t)e * 16];
  float4 w0 = *(const float4*)&We[0], w1 = *(const float4*)&We[4];
  float4 w2 = *(const float4*)&We[8], w3 = *(const float4*)&We[12];
  float4 a0 = p[0], a1 = p[1], a2 = p[2], a3 = p[3];
  float s = a0.x * w0.x + a0.y * w0.y + a0.z * w0.z + a0.w * w0.w
          + a1.x * w1.x + a1.y * w1.y + a1.z * w1.z + a1.w * w1.w
          + a2.x * w2.x + a2.y * w2.y + a2.z * w2.z + a2.w * w2.w
          + a3.x * w3.x + a3.y * w3.y + a3.z * w3.z + a3.w * w3.w;
  Eb[e] = s + be[0];
}

// ---------------------------------------------------------------------------
// XCD-grouped slab scatter: 8 src groups; 8 prefetched src reads per thread;
// matching edges read only dst + Eb (L2-hot 4 B each).
// ---------------------------------------------------------------------------
__global__ void scatter8(const int* __restrict__ ei,
                         const float* __restrict__ Eb,
                         int* __restrict__ cnt,
                         int2* __restrict__ slabDE, int E, int N)
{
  int grp = blockIdx.x & 7;
  int blk = blockIdx.x >> 3;
  int lo = grp * (N >> 3), hi = lo + (N >> 3);
  int per = E >> 8;                 // 2048-edge window
  int base = blk * per;
  int srcs[8];
#pragma unroll
  for (int w = 0; w < 8; ++w) srcs[w] = ei[base + w * 256 + threadIdx.x];
#pragma unroll
  for (int w = 0; w < 8; ++w) {
    int src = srcs[w];
    if (src < lo || src >= hi) continue;
    int e = base + w * 256 + threadIdx.x;
    int dst = ei[E + e];
    float s = Eb[e];
    int pos = atomicAdd(&cnt[src], 1);
    if (pos < SLAB) {
      int2 rec; rec.x = dst; rec.y = __float_as_int(s);
      slabDE[src * SLAB + pos] = rec;
    }
  }
}

// ---------------------------------------------------------------------------
// Fused attention (R13 version: 2 edges in flight per 8-lane subteam) +
// dedup + sparse softmax + P@V + residual + banked BN1 stats.
// ---------------------------------------------------------------------------
__global__ __launch_bounds__(256) void attn_fused(
    const float* __restrict__ x, const float* __restrict__ Q,
    const unsigned short* __restrict__ Kbf, const unsigned short* __restrict__ Vbf,
    const float* __restrict__ SVp, const int* __restrict__ cnt,
    const int2* __restrict__ slabDE,
    float* __restrict__ h1, float* __restrict__ sum1p, float* __restrict__ sq1p,
    int N)
{
  __shared__ float sv[8][SLAB];
  __shared__ int sd[8][SLAB];
  __shared__ unsigned char sown[8][SLAB];
  __shared__ float csum[H], csq[H], svf[H];
  int tid = threadIdx.x;
  int team = tid >> 5, lane = tid & 31;
  int i = blockIdx.x * 8 + team;
  int k = cnt[i]; if (k > SLAB) k = SLAB;
  int base = i * SLAB;

  if (tid < H) {
    csum[tid] = 0.f; csq[tid] = 0.f;
    float s = 0.f;
#pragma unroll
    for (int b = 0; b < 8; ++b) s += SVp[b * H + tid];
    svf[tid] = s;
  }

  for (int p = lane; p < k; p += 32) {
    int2 de = slabDE[base + p];
    sd[team][p] = de.x;
    sv[team][p] = __int_as_float(de.y);
  }
  __syncthreads();

  int sub8 = lane & 7, sub4 = lane >> 3;
  const float4* q4 = (const float4*)(Q + (size_t)i * H);
  float4 qa0 = q4[2 * sub8], qa1 = q4[2 * sub8 + 1];
  float4 qb0 = q4[16 + 2 * sub8], qb1 = q4[17 + 2 * sub8];
  for (int p0 = sub4 * 2; p0 < k; p0 += 8) {
    int d0 = sd[team][p0];
    bool has1 = (p0 + 1 < k);
    int d1 = has1 ? sd[team][p0 + 1] : d0;
    const s16x8* k0 = (const s16x8*)(Kbf + (size_t)d0 * H);
    const s16x8* k1 = (const s16x8*)(Kbf + (size_t)d1 * H);
    s16x8 ka0 = k0[sub8], kb0 = k0[8 + sub8];
    s16x8 ka1 = k1[sub8], kb1 = k1[8 + sub8];
    float p0_, p1_;
    p0_ = qa0.x * bf2f((unsigned short)ka0[0]) + qa0.y * bf2f((unsigned short)ka0[1])
        + qa0.z * bf2f((unsigned short)ka0[2]) + qa0.w * bf2f((unsigned short)ka0[3])
        + qa1.x * bf2f((unsigned short)ka0[4]) + qa1.y * bf2f((unsigned short)ka0[5])
        + qa1.z * bf2f((unsigned short)ka0[6]) + qa1.w * bf2f((unsigned short)ka0[7])
        + qb0.x * bf2f((unsigned short)kb0[0]) + qb0.y * bf2f((unsigned short)kb0[1])
        + qb0.z * bf2f((unsigned short)kb0[2]) + qb0.w * bf2f((unsigned short)kb0[3])
        + qb1.x * bf2f((unsigned short)kb0[4]) + qb1.y * bf2f((unsigned short)kb0[5])
        + qb1.z * bf2f((unsigned short)kb0[6]) + qb1.w * bf2f((unsigned short)kb0[7]);
    p1_ = qa0.x * bf2f((unsigned short)ka1[0]) + qa0.y * bf2f((unsigned short)ka1[1])
        + qa0.z * bf2f((unsigned short)ka1[2]) + qa0.w * bf2f((unsigned short)ka1[3])
        + qa1.x * bf2f((unsigned short)ka1[4]) + qa1.y * bf2f((unsigned short)ka1[5])
        + qa1.z * bf2f((unsigned short)ka1[6]) + qa1.w * bf2f((unsigned short)ka1[7])
        + qb0.x * bf2f((unsigned short)kb1[0]) + qb0.y * bf2f((unsigned short)kb1[1])
        + qb0.z * bf2f((unsigned short)kb1[2]) + qb0.w * bf2f((unsigned short)kb1[3])
        + qb1.x * bf2f((unsigned short)kb1[4]) + qb1.y * bf2f((unsigned short)kb1[5])
        + qb1.z * bf2f((unsigned short)kb1[6]) + qb1.w * bf2f((unsigned short)kb1[7]);
    p0_ += __shfl_xor(p0_, 1); p1_ += __shfl_xor(p1_, 1);
    p0_ += __shfl_xor(p0_, 2); p1_ += __shfl_xor(p1_, 2);
    p0_ += __shfl_xor(p0_, 4); p1_ += __shfl_xor(p1_, 4);
    if (sub8 == 0) {
      float s0 = p0_ + sv[team][p0];
      sv[team][p0] = (s0 >= 0.f) ? s0 : 0.01f * s0;
      if (has1) {
        float s1 = p1_ + sv[team][p0 + 1];
        sv[team][p0 + 1] = (s1 >= 0.f) ? s1 : 0.01f * s1;
      }
    }
  }

  for (int p = lane; p < k; p += 32) {
    int d = sd[team][p], o = p;
    for (int q = 0; q < p; ++q)
      if (sd[team][q] == d) { o = q; break; }
    sown[team][p] = (unsigned char)o;
  }
  for (int p = lane; p < k; p += 32)
    if (sown[team][p] != (unsigned char)p)
      atomicAdd(&sv[team][sown[team][p]], sv[team][p]);

  float m = 0.f;
  for (int p = lane; p < k; p += 32)
    if (sown[team][p] == (unsigned char)p) m = fmaxf(m, sv[team][p]);
#pragma unroll
  for (int mask = 16; mask; mask >>= 1) m = fmaxf(m, __shfl_xor(m, mask));
  float em = expf(-m);

  float zl = 0.f;
  for (int p = lane; p < k; p += 32) {
    float cf = 0.f;
    if (sown[team][p] == (unsigned char)p) cf = expf(sv[team][p] - m) - em;
    sv[team][p] = cf;
    zl += cf;
  }
#pragma unroll
  for (int mask = 16; mask; mask >>= 1) zl += __shfl_xor(zl, mask);
  float Zi = 1.f / ((float)N * em + zl);

  const ushort4* V4 = (const ushort4*)Vbf;
  float4 s4 = *(const float4*)&svf[lane * 4];
  float ax = em * s4.x, ay = em * s4.y, az = em * s4.z, aw = em * s4.w;
  int c = 0;
  for (; c + 8 <= k; c += 8) {
    float cf[8]; int dd[8]; ushort4 vv[8];
#pragma unroll
    for (int u = 0; u < 8; ++u) { cf[u] = sv[team][c + u]; dd[u] = sd[team][c + u]; }
#pragma unroll
    for (int u = 0; u < 8; ++u) vv[u] = V4[(size_t)dd[u] * 32 + lane];
#pragma unroll
    for (int u = 0; u < 8; ++u) {
      ax += cf[u] * bf2f(vv[u].x);
      ay += cf[u] * bf2f(vv[u].y);
      az += cf[u] * bf2f(vv[u].z);
      aw += cf[u] * bf2f(vv[u].w);
    }
  }
  for (; c < k; ++c) {
    float cf = sv[team][c];
    ushort4 v0 = V4[(size_t)sd[team][c] * 32 + lane];
    ax += cf * bf2f(v0.x); ay += cf * bf2f(v0.y);
    az += cf * bf2f(v0.z); aw += cf * bf2f(v0.w);
  }
  float4 xx = *(const float4*)&x[(size_t)i * H + lane * 4];
  float4 out;
  out.x = xx.x + ax * Zi; out.y = xx.y + ay * Zi;
  out.z = xx.z + az * Zi; out.w = xx.w + aw * Zi;
  *(float4*)&h1[(size_t)i * H + lane * 4] = out;

  int c0 = lane * 4;
  atomicAdd(&csum[c0 + 0], out.x); atomicAdd(&csq[c0 + 0], out.x * out.x);
  atomicAdd(&csum[c0 + 1], out.y); atomicAdd(&csq[c0 + 1], out.y * out.y);
  atomicAdd(&csum[c0 + 2], out.z); atomicAdd(&csq[c0 + 2], out.z * out.z);
  atomicAdd(&csum[c0 + 3], out.w); atomicAdd(&csq[c0 + 3], out.w * out.w);
  __syncthreads();
  if (tid < H) {
    int bank = blockIdx.x & 15;
    atomicAdd(&sum1p[bank * H + tid], csum[tid]);
    atomicAdd(&sq1p[bank * H + tid], csq[tid]);
  }
}

// ---------------------------------------------------------------------------
// Fused FFN (banked-stats): folds sum1p/sq1p in prologue; t1 tile in LDS only;
// writes BN2 partial sums to 16 banks.
// ---------------------------------------------------------------------------
__global__ __launch_bounds__(256) void ffn_fused(
    const float* __restrict__ h1, const short* __restrict__ W1h,
    const float* __restrict__ b1, const short* __restrict__ W2h,
    const float* __restrict__ b2,
    const float* __restrict__ sum1p, const float* __restrict__ sq1p,
    const float* __restrict__ g1, const float* __restrict__ bb1,
    float* __restrict__ h2, float* __restrict__ sum2p, float* __restrict__ sq2p,
    float invN)
{
  __shared__ __align__(16) short As[32 * LDA];
  __shared__ __align__(16) short Ts[32 * LDA2];
  __shared__ float aF[H], bF[H];
  int tid = threadIdx.x;
  int bm = blockIdx.x * 32;
  int wave = tid >> 6, lane = tid & 63;
  int quad = lane >> 4, l16 = lane & 15;

  if (tid < H) {
    float s = 0.f, q = 0.f;
#pragma unroll
    for (int b = 0; b < 16; ++b) { s += sum1p[b * H + tid]; q += sq1p[b * H + tid]; }
    float mu = s * invN;
    float var = q * invN - mu * mu;
    float rs = rsqrtf(var + EPS);
    float a = g1[tid] * rs;
    aF[tid] = a;
    bF[tid] = bb1[tid] - a * mu;
  }
  __syncthreads();

  int f = tid & 15;
#pragma unroll
  for (int i = 0; i < 2; ++i) {
    int g = i * 256 + tid;
    int row = g >> 4;
    const float4* xp = (const float4*)&h1[(size_t)(bm + row) * H + f * 8];
    float4 v0 = xp[0], v1 = xp[1];
    float vv[8] = {v0.x, v0.y, v0.z, v0.w, v1.x, v1.y, v1.z, v1.w};
    s16x8 hv;
#pragma unroll
    for (int j = 0; j < 8; ++j) {
      int c = f * 8 + j;
      hv[j] = (short)f2bf(aF[c] * vv[j] + bF[c]);
    }
    *(s16x8*)&As[row * LDA + f * 8] = hv;
  }

  int wn1 = wave * 64;
  s16x8 b1f[4][4];
#pragma unroll
  for (int nt = 0; nt < 4; ++nt)
#pragma unroll
    for (int ks = 0; ks < 4; ++ks)
      b1f[nt][ks] = *(const s16x8*)&W1h[(size_t)(wn1 + nt * 16 + l16) * H + ks * 32 + quad * 8];
  __syncthreads();

  f32x4 acc1[2][4];
#pragma unroll
  for (int mt = 0; mt < 2; ++mt)
#pragma unroll
    for (int nt = 0; nt < 4; ++nt) acc1[mt][nt] = (f32x4){0.f, 0.f, 0.f, 0.f};

#pragma unroll
  for (int ks = 0; ks < 4; ++ks) {
    int kof = ks * 32 + quad * 8;
    s16x8 ah[2];
#pragma unroll
    for (int mt = 0; mt < 2; ++mt) ah[mt] = *(s16x8*)&As[(mt * 16 + l16) * LDA + kof];
#pragma unroll
    for (int mt = 0; mt < 2; ++mt)
#pragma unroll
      for (int nt = 0; nt < 4; ++nt)
        acc1[mt][nt] = __builtin_amdgcn_mfma_f32_16x16x32_bf16(ah[mt], b1f[nt][ks], acc1[mt][nt], 0, 0, 0);
  }

#pragma unroll
  for (int nt = 0; nt < 4; ++nt) {
    int col = wn1 + nt * 16 + l16;
    float bb = b1[col];
#pragma unroll
    for (int mt = 0; mt < 2; ++mt)
#pragma unroll
      for (int r = 0; r < 4; ++r) {
        int row = mt * 16 + quad * 4 + r;
        float v = acc1[mt][nt][r] + bb;
        v = v > 0.f ? v : 0.f;
        Ts[row * LDA2 + col] = (short)f2bf(v);
      }
  }

  int wn2 = wave * 32;
  s16x8 b2f[2][8];
#pragma unroll
  for (int nt = 0; nt < 2; ++nt)
#pragma unroll
    for (int ks = 0; ks < 8; ++ks)
      b2f[nt][ks] = *(const s16x8*)&W2h[(size_t)(wn2 + nt * 16 + l16) * H2 + ks * 32 + quad * 8];
  __syncthreads();

  f32x4 acc2[2][2];
#pragma unroll
  for (int mt = 0; mt < 2; ++mt)
#pragma unroll
    for (int nt = 0; nt < 2; ++nt) acc2[mt][nt] = (f32x4){0.f, 0.f, 0.f, 0.f};

#pragma unroll
  for (int ks = 0; ks < 8; ++ks) {
    int kof = ks * 32 + quad * 8;
    s16x8 ah[2];
#pragma unroll
    for (int mt = 0; mt < 2; ++mt) ah[mt] = *(s16x8*)&Ts[(mt * 16 + l16) * LDA2 + kof];
#pragma unroll
    for (int mt = 0; mt < 2; ++mt)
#pragma unroll
      for (int nt = 0; nt < 2; ++nt)
        acc2[mt][nt] = __builtin_amdgcn_mfma_f32_16x16x32_bf16(ah[mt], b2f[nt][ks], acc2[mt][nt], 0, 0, 0);
  }

  int bank = blockIdx.x & 15;
#pragma unroll
  for (int nt = 0; nt < 2; ++nt) {
    int col = wn2 + nt * 16 + l16;
    float ra = aF[col], rb = bF[col];
    float bb = b2[col];
    float ps = 0.f, pq = 0.f;
#pragma unroll
    for (int mt = 0; mt < 2; ++mt)
#pragma unroll
      for (int r = 0; r < 4; ++r) {
        int row = bm + mt * 16 + quad * 4 + r;
        float rr = ra * h1[(size_t)row * H + col] + rb;
        float v = acc2[mt][nt][r] + bb + rr;
        h2[(size_t)row * H + col] = v;
        ps += v; pq += v * v;
      }
    ps += __shfl_xor(ps, 16); ps += __shfl_xor(ps, 32);
    pq += __shfl_xor(pq, 16); pq += __shfl_xor(pq, 32);
    if (quad == 0) {
      atomicAdd(&sum2p[bank * H + col], ps);
      atomicAdd(&sq2p[bank * H + col], pq);
    }
  }
}

// BN2: fold 16 banks -> affine in LDS, then vectorized apply.
__global__ __launch_bounds__(256) void bn_apply(
    const float* __restrict__ X,
    const float* __restrict__ sum2p, const float* __restrict__ sq2p,
    const float* __restrict__ g2, const float* __restrict__ bb2,
    float* __restrict__ Y, size_t n4, float invN)
{
  __shared__ float A2s[H], B2s[H];
  int tid = threadIdx.x;
  if (tid < H) {
    float s = 0.f, q = 0.f;
#pragma unroll
    for (int b = 0; b < 16; ++b) { s += sum2p[b * H + tid]; q += sq2p[b * H + tid]; }
    float mu = s * invN;
    float var = q * invN - mu * mu;
    float rs = rsqrtf(var + EPS);
    float a = g2[tid] * rs;
    A2s[tid] = a;
    B2s[tid] = bb2[tid] - a * mu;
  }
  __syncthreads();
  size_t i = (size_t)blockIdx.x * blockDim.x + tid;
  if (i >= n4) return;
  float4 v = ((const float4*)X)[i];
  int c = (int)((i * 4) & (H - 1));
  float4 a = *(const float4*)&A2s[c];
  float4 b = *(const float4*)&B2s[c];
  v.x = a.x * v.x + b.x; v.y = a.y * v.y + b.y;
  v.z = a.z * v.z + b.z; v.w = a.w * v.w + b.w;
  ((float4*)Y)[i] = v;
}

// ---------------------------------------------------------------------------
extern "C" void kernel_launch(void* const* d_in, const int* in_sizes, int n_in,
                              void* d_out, int out_size, void* d_ws, size_t ws_size,
                              hipStream_t stream)
{
  const float* x  = (const float*)d_in[0];
  const int*   ei = (const int*)d_in[1];
  const float* ea = (const float*)d_in[2];
  const float* Wq = (const float*)d_in[3];
  const float* bq = (const float*)d_in[4];
  const float* Wk = (const float*)d_in[5];
  const float* bk = (const float*)d_in[6];
  const float* Wv = (const float*)d_in[7];
  const float* bv = (const float*)d_in[8];
  const float* We = (const float*)d_in[9];
  const float* be = (const float*)d_in[10];
  const float* g1 = (const float*)d_in[11];
  const float* bb1 = (const float*)d_in[12];
  const float* W1 = (const float*)d_in[13];
  const float* b1 = (const float*)d_in[14];
  const float* W2 = (const float*)d_in[15];
  const float* b2 = (const float*)d_in[16];
  const float* g2 = (const float*)d_in[17];
  const float* bb2 = (const float*)d_in[18];

  int N = in_sizes[0] / H;      // 16384
  int E = in_sizes[2] / 16;     // 524288
  size_t NH = (size_t)N * H;
  float invN = 1.0f / (float)N;

  float* Q   = (float*)d_ws;                         // 8 MB
  float* KmSlot = Q + NH;                            // 8 MB (Kbf + later h2)
  float* h1  = KmSlot + NH;                          // 8 MB
  unsigned short* Vbf = (unsigned short*)(h1 + NH);  // 4 MB
  int2*  slabDE = (int2*)(Vbf + NH);                 // 12 MB
  float* Eb     = (float*)(slabDE + (size_t)N * SLAB);  // 2 MB
  int*   cnt    = (int*)(Eb + E);
  float* stats  = (float*)(cnt + N);
  float* SVp   = stats;
  float* sum1p = stats + 8 * H;
  float* sq1p  = sum1p + 16 * H;
  float* sum2p = sq1p + 16 * H;
  float* sq2p  = sum2p + 16 * H;
  float* statsEnd = sq2p + 16 * H;      // 72*H floats total
  short* wbuf = (short*)statsEnd;
  short* Wqh = wbuf;
  short* Wql = Wqh + 16384;
  short* Wkh = Wql + 16384;
  short* Wkl = Wkh + 16384;
  short* Wvh = Wkl + 16384;
  short* W1h = Wvh + 16384;
  short* W2h = W1h + 32768;
  unsigned short* Kbf = (unsigned short*)KmSlot;  // 4 MB, dead after attn_fused
  float* h2 = KmSlot;                             // alias (Kbf dead after attn)

  hipMemsetAsync(cnt, 0, (size_t)N * sizeof(int), stream);
  hipMemsetAsync(stats, 0, (size_t)72 * H * sizeof(float), stream);

  wprep<<<dim3(128, 1, 5), 256, 0, stream>>>(Wq, Wk, Wv, W1, W2,
      Wqh, Wql, Wkh, Wkl, Wvh, W1h, W2h);

  qkv_mfma<<<dim3(N / 64), 256, 0, stream>>>(
      x, Wqh, Wql, Wkh, Wkl, Wvh, bq, bk, bv, Q, Kbf, Vbf, SVp);

  eb_compute<<<dim3((E + 255) / 256), 256, 0, stream>>>(ea, We, be, Eb, E);
  scatter8<<<dim3(2048), 256, 0, stream>>>(ei, Eb, cnt, slabDE, E, N);

  attn_fused<<<dim3(N / 8), 256, 0, stream>>>(x, Q, Kbf, Vbf, SVp, cnt, slabDE,
                                              h1, sum1p, sq1p, N);

  ffn_fused<<<dim3(N / 32), 256, 0, stream>>>(h1, W1h, b1, W2h, b2,
      sum1p, sq1p, g1, bb1, h2, sum2p, sq2p, invN);

  bn_apply<<<dim3((int)((NH / 4 + 255) / 256)), 256, 0, stream>>>(
      h2, sum2p, sq2p, g2, bb2, (float*)d_out, NH / 4, invN);
}

// Round 16
// 222.747 us; speedup vs baseline: 1.0714x; 1.0319x over previous
//
#include <hip/hip_runtime.h>
#include <hip/hip_bf16.h>
#include <math.h>

#define H 128
#define H2 256
#define SLAB 96    // slots per row; P(Poisson(32) > 96) ~ 1e-18
#define LDA 136    // LDS row pitch (shorts) for K=128 tiles
#define LDA2 264   // LDS row pitch (shorts) for K=256 tiles
#define EPS 1e-5f

typedef __attribute__((ext_vector_type(8))) short s16x8;
typedef __attribute__((ext_vector_type(4))) float f32x4;

__device__ __forceinline__ unsigned short f2bf(float f) {
  unsigned u = __float_as_uint(f);
  unsigned r = (u + 0x7FFFu + ((u >> 16) & 1u)) >> 16;
  return (unsigned short)r;
}
__device__ __forceinline__ float bf2f(unsigned short s) {
  return __uint_as_float(((unsigned)s) << 16);
}

// ---------------------------------------------------------------------------
// Weight prep: transpose to [n][k] + bf16 (split hi/lo for Wq, Wk).
// job z==5 zeroes cnt + banked stats (replaces two memset dispatches).
// ---------------------------------------------------------------------------
__global__ void wprep(const float* __restrict__ Wq, const float* __restrict__ Wk,
                      const float* __restrict__ Wv, const float* __restrict__ W1,
                      const float* __restrict__ W2,
                      short* qh, short* ql, short* kh, short* kl,
                      short* vh, short* w1h, short* w2h,
                      int* __restrict__ cnt, float* __restrict__ stats, int N)
{
  int job = blockIdx.z;
  if (job == 5) {
    int t = blockIdx.x * 256 + threadIdx.x;   // 0..32767
    if (t < N) cnt[t] = 0;
    if (t < 72 * H) stats[t] = 0.f;
    return;
  }
  const float* src; short* dh; short* dl = nullptr; int Kd, Nn;
  if (job == 0)      { src = Wq; dh = qh;  dl = ql; Kd = 128; Nn = 128; }
  else if (job == 1) { src = Wk; dh = kh;  dl = kl; Kd = 128; Nn = 128; }
  else if (job == 2) { src = Wv; dh = vh;           Kd = 128; Nn = 128; }
  else if (job == 3) { src = W1; dh = w1h;          Kd = 128; Nn = 256; }
  else               { src = W2; dh = w2h;          Kd = 256; Nn = 128; }
  int t = blockIdx.x * 256 + threadIdx.x;
  if (t >= Kd * Nn) return;
  int n = t / Kd, k = t - n * Kd;
  float v = src[(size_t)k * Nn + n];
  unsigned short h = f2bf(v);
  dh[t] = (short)h;
  if (dl) dl[t] = (short)f2bf(v - bf2f(h));
}

// ---------------------------------------------------------------------------
// QKV via MFMA. 64-row M-tile, 256 threads. A split hi/lo staged once in LDS;
// B fragments direct from L2-hot [n][k] bf16 weights. SV goes to 8 banks.
// ---------------------------------------------------------------------------
__global__ __launch_bounds__(256) void qkv_mfma(
    const float* __restrict__ x,
    const short* __restrict__ Wqh, const short* __restrict__ Wql,
    const short* __restrict__ Wkh, const short* __restrict__ Wkl,
    const short* __restrict__ Wvh,
    const float* __restrict__ bq, const float* __restrict__ bk,
    const float* __restrict__ bv,
    float* __restrict__ Q, unsigned short* __restrict__ Kbf,
    unsigned short* __restrict__ Vbf, float* __restrict__ SVp)
{
  __shared__ __align__(16) short Ahi[64 * LDA];
  __shared__ __align__(16) short Alo[64 * LDA];
  int tid = threadIdx.x;
  int bm = blockIdx.x * 64;
  int wave = tid >> 6, lane = tid & 63;
  int quad = lane >> 4, l16 = lane & 15;
  int wn = wave * 32;

#pragma unroll
  for (int i = 0; i < 4; ++i) {
    int g = i * 256 + tid;
    int row = g >> 4, f = g & 15;
    const float4* xp = (const float4*)&x[(size_t)(bm + row) * H + f * 8];
    float4 v0 = xp[0], v1 = xp[1];
    float vv[8] = {v0.x, v0.y, v0.z, v0.w, v1.x, v1.y, v1.z, v1.w};
    s16x8 hv, lv;
#pragma unroll
    for (int j = 0; j < 8; ++j) {
      unsigned short hh = f2bf(vv[j]);
      hv[j] = (short)hh;
      lv[j] = (short)f2bf(vv[j] - bf2f(hh));
    }
    *(s16x8*)&Ahi[row * LDA + f * 8] = hv;
    *(s16x8*)&Alo[row * LDA + f * 8] = lv;
  }
  __syncthreads();

  for (int ph = 0; ph < 3; ++ph) {
    const short* Bh = (ph == 0) ? Wqh : (ph == 1) ? Wkh : Wvh;
    const short* Bl = (ph == 0) ? Wql : (ph == 1) ? Wkl : nullptr;

    s16x8 bh[2][4], bl2[2][4];
#pragma unroll
    for (int nt = 0; nt < 2; ++nt)
#pragma unroll
      for (int ks = 0; ks < 4; ++ks)
        bh[nt][ks] = *(const s16x8*)&Bh[(size_t)(wn + nt * 16 + l16) * H + ks * 32 + quad * 8];
    if (Bl) {
#pragma unroll
      for (int nt = 0; nt < 2; ++nt)
#pragma unroll
        for (int ks = 0; ks < 4; ++ks)
          bl2[nt][ks] = *(const s16x8*)&Bl[(size_t)(wn + nt * 16 + l16) * H + ks * 32 + quad * 8];
    }

    f32x4 acc[4][2];
#pragma unroll
    for (int mt = 0; mt < 4; ++mt)
#pragma unroll
      for (int nt = 0; nt < 2; ++nt) acc[mt][nt] = (f32x4){0.f, 0.f, 0.f, 0.f};

#pragma unroll
    for (int ks = 0; ks < 4; ++ks) {
      int kof = ks * 32 + quad * 8;
      s16x8 ah[4], al[4];
#pragma unroll
      for (int mt = 0; mt < 4; ++mt) {
        ah[mt] = *(s16x8*)&Ahi[(mt * 16 + l16) * LDA + kof];
        al[mt] = *(s16x8*)&Alo[(mt * 16 + l16) * LDA + kof];
      }
#pragma unroll
      for (int mt = 0; mt < 4; ++mt)
#pragma unroll
        for (int nt = 0; nt < 2; ++nt) {
          acc[mt][nt] = __builtin_amdgcn_mfma_f32_16x16x32_bf16(ah[mt], bh[nt][ks], acc[mt][nt], 0, 0, 0);
          if (ph < 2) {
            acc[mt][nt] = __builtin_amdgcn_mfma_f32_16x16x32_bf16(ah[mt], bl2[nt][ks], acc[mt][nt], 0, 0, 0);
            acc[mt][nt] = __builtin_amdgcn_mfma_f32_16x16x32_bf16(al[mt], bh[nt][ks], acc[mt][nt], 0, 0, 0);
          }
        }
    }

    if (ph == 0) {
#pragma unroll
      for (int nt = 0; nt < 2; ++nt) {
        int col = wn + nt * 16 + l16;
        float bb = bq[col];
#pragma unroll
        for (int mt = 0; mt < 4; ++mt)
#pragma unroll
          for (int r = 0; r < 4; ++r) {
            int row = bm + mt * 16 + quad * 4 + r;
            Q[(size_t)row * H + col] = acc[mt][nt][r] + bb;
          }
      }
    } else if (ph == 1) {
#pragma unroll
      for (int nt = 0; nt < 2; ++nt) {
        int col = wn + nt * 16 + l16;
        float bb = bk[col];
#pragma unroll
        for (int mt = 0; mt < 4; ++mt)
#pragma unroll
          for (int r = 0; r < 4; ++r) {
            int row = bm + mt * 16 + quad * 4 + r;
            Kbf[(size_t)row * H + col] = f2bf(acc[mt][nt][r] + bb);
          }
      }
    } else {
      int bank = blockIdx.x & 7;
#pragma unroll
      for (int nt = 0; nt < 2; ++nt) {
        int col = wn + nt * 16 + l16;
        float bb = bv[col];
        float ps = 0.f;
#pragma unroll
        for (int mt = 0; mt < 4; ++mt)
#pragma unroll
          for (int r = 0; r < 4; ++r) {
            int row = bm + mt * 16 + quad * 4 + r;
            float v = acc[mt][nt][r] + bb;
            Vbf[(size_t)row * H + col] = f2bf(v);
            ps += v;
          }
        ps += __shfl_xor(ps, 16);
        ps += __shfl_xor(ps, 32);
        if (quad == 0) atomicAdd(&SVp[bank * H + col], ps);
      }
    }
  }
}

// ---------------------------------------------------------------------------
// XCD-grouped edge scatter (grouped single-kernel version — R13 proven).
// ---------------------------------------------------------------------------
__global__ void ebfill(const float* __restrict__ ea,
                       const float* __restrict__ We,
                       const float* __restrict__ be,
                       const int* __restrict__ ei,
                       int* __restrict__ cnt,
                       int2* __restrict__ slabDE, int E, int N)
{
  int grp = blockIdx.x & 7;
  int blk = blockIdx.x >> 3;
  int lo = grp * (N >> 3), hi = lo + (N >> 3);
  int per = E >> 8;                 // edges per window (2048)
  int base = blk * per;
  float4 w0 = *(const float4*)&We[0], w1 = *(const float4*)&We[4];
  float4 w2 = *(const float4*)&We[8], w3 = *(const float4*)&We[12];
  float bias = be[0];
  for (int i = 0; i < per; i += 256) {
    int e = base + i + threadIdx.x;
    if (e >= E) continue;
    int src = ei[e];
    if (src < lo || src >= hi) continue;
    int dst = ei[E + e];
    const float4* p = (const float4*)&ea[(size_t)e * 16];
    float4 a0 = p[0], a1 = p[1], a2 = p[2], a3 = p[3];
    float s = a0.x * w0.x + a0.y * w0.y + a0.z * w0.z + a0.w * w0.w
            + a1.x * w1.x + a1.y * w1.y + a1.z * w1.z + a1.w * w1.w
            + a2.x * w2.x + a2.y * w2.y + a2.z * w2.z + a2.w * w2.w
            + a3.x * w3.x + a3.y * w3.y + a3.z * w3.z + a3.w * w3.w;
    s += bias;
    int pos = atomicAdd(&cnt[src], 1);
    if (pos < SLAB) {
      int2 rec; rec.x = dst; rec.y = __float_as_int(s);
      slabDE[src * SLAB + pos] = rec;
    }
  }
}

// ---------------------------------------------------------------------------
// Fused attention (2 edges in flight per 8-lane subteam) + dedup +
// sparse softmax vs dense-zero background + P@V + residual + banked BN1 stats.
// ---------------------------------------------------------------------------
__global__ __launch_bounds__(256) void attn_fused(
    const float* __restrict__ x, const float* __restrict__ Q,
    const unsigned short* __restrict__ Kbf, const unsigned short* __restrict__ Vbf,
    const float* __restrict__ SVp, const int* __restrict__ cnt,
    const int2* __restrict__ slabDE,
    float* __restrict__ h1, float* __restrict__ sum1p, float* __restrict__ sq1p,
    int N)
{
  __shared__ float sv[8][SLAB];
  __shared__ int sd[8][SLAB];
  __shared__ unsigned char sown[8][SLAB];
  __shared__ float csum[H], csq[H], svf[H];
  int tid = threadIdx.x;
  int team = tid >> 5, lane = tid & 31;
  int i = blockIdx.x * 8 + team;
  int k = cnt[i]; if (k > SLAB) k = SLAB;
  int base = i * SLAB;

  if (tid < H) {
    csum[tid] = 0.f; csq[tid] = 0.f;
    float s = 0.f;
#pragma unroll
    for (int b = 0; b < 8; ++b) s += SVp[b * H + tid];
    svf[tid] = s;
  }

  for (int p = lane; p < k; p += 32) {
    int2 de = slabDE[base + p];
    sd[team][p] = de.x;
    sv[team][p] = __int_as_float(de.y);
  }
  __syncthreads();

  int sub8 = lane & 7, sub4 = lane >> 3;
  const float4* q4 = (const float4*)(Q + (size_t)i * H);
  float4 qa0 = q4[2 * sub8], qa1 = q4[2 * sub8 + 1];
  float4 qb0 = q4[16 + 2 * sub8], qb1 = q4[17 + 2 * sub8];
  for (int p0 = sub4 * 2; p0 < k; p0 += 8) {
    int d0 = sd[team][p0];
    bool has1 = (p0 + 1 < k);
    int d1 = has1 ? sd[team][p0 + 1] : d0;
    const s16x8* k0 = (const s16x8*)(Kbf + (size_t)d0 * H);
    const s16x8* k1 = (const s16x8*)(Kbf + (size_t)d1 * H);
    s16x8 ka0 = k0[sub8], kb0 = k0[8 + sub8];
    s16x8 ka1 = k1[sub8], kb1 = k1[8 + sub8];
    float p0_, p1_;
    p0_ = qa0.x * bf2f((unsigned short)ka0[0]) + qa0.y * bf2f((unsigned short)ka0[1])
        + qa0.z * bf2f((unsigned short)ka0[2]) + qa0.w * bf2f((unsigned short)ka0[3])
        + qa1.x * bf2f((unsigned short)ka0[4]) + qa1.y * bf2f((unsigned short)ka0[5])
        + qa1.z * bf2f((unsigned short)ka0[6]) + qa1.w * bf2f((unsigned short)ka0[7])
        + qb0.x * bf2f((unsigned short)kb0[0]) + qb0.y * bf2f((unsigned short)kb0[1])
        + qb0.z * bf2f((unsigned short)kb0[2]) + qb0.w * bf2f((unsigned short)kb0[3])
        + qb1.x * bf2f((unsigned short)kb0[4]) + qb1.y * bf2f((unsigned short)kb0[5])
        + qb1.z * bf2f((unsigned short)kb0[6]) + qb1.w * bf2f((unsigned short)kb0[7]);
    p1_ = qa0.x * bf2f((unsigned short)ka1[0]) + qa0.y * bf2f((unsigned short)ka1[1])
        + qa0.z * bf2f((unsigned short)ka1[2]) + qa0.w * bf2f((unsigned short)ka1[3])
        + qa1.x * bf2f((unsigned short)ka1[4]) + qa1.y * bf2f((unsigned short)ka1[5])
        + qa1.z * bf2f((unsigned short)ka1[6]) + qa1.w * bf2f((unsigned short)ka1[7])
        + qb0.x * bf2f((unsigned short)kb1[0]) + qb0.y * bf2f((unsigned short)kb1[1])
        + qb0.z * bf2f((unsigned short)kb1[2]) + qb0.w * bf2f((unsigned short)kb1[3])
        + qb1.x * bf2f((unsigned short)kb1[4]) + qb1.y * bf2f((unsigned short)kb1[5])
        + qb1.z * bf2f((unsigned short)kb1[6]) + qb1.w * bf2f((unsigned short)kb1[7]);
    p0_ += __shfl_xor(p0_, 1); p1_ += __shfl_xor(p1_, 1);
    p0_ += __shfl_xor(p0_, 2); p1_ += __shfl_xor(p1_, 2);
    p0_ += __shfl_xor(p0_, 4); p1_ += __shfl_xor(p1_, 4);
    if (sub8 == 0) {
      float s0 = p0_ + sv[team][p0];
      sv[team][p0] = (s0 >= 0.f) ? s0 : 0.01f * s0;
      if (has1) {
        float s1 = p1_ + sv[team][p0 + 1];
        sv[team][p0 + 1] = (s1 >= 0.f) ? s1 : 0.01f * s1;
      }
    }
  }

  for (int p = lane; p < k; p += 32) {
    int d = sd[team][p], o = p;
    for (int q = 0; q < p; ++q)
      if (sd[team][q] == d) { o = q; break; }
    sown[team][p] = (unsigned char)o;
  }
  for (int p = lane; p < k; p += 32)
    if (sown[team][p] != (unsigned char)p)
      atomicAdd(&sv[team][sown[team][p]], sv[team][p]);

  float m = 0.f;
  for (int p = lane; p < k; p += 32)
    if (sown[team][p] == (unsigned char)p) m = fmaxf(m, sv[team][p]);
#pragma unroll
  for (int mask = 16; mask; mask >>= 1) m = fmaxf(m, __shfl_xor(m, mask));
  float em = expf(-m);

  float zl = 0.f;
  for (int p = lane; p < k; p += 32) {
    float cf = 0.f;
    if (sown[team][p] == (unsigned char)p) cf = expf(sv[team][p] - m) - em;
    sv[team][p] = cf;
    zl += cf;
  }
#pragma unroll
  for (int mask = 16; mask; mask >>= 1) zl += __shfl_xor(zl, mask);
  float Zi = 1.f / ((float)N * em + zl);

  const ushort4* V4 = (const ushort4*)Vbf;
  float4 s4 = *(const float4*)&svf[lane * 4];
  float ax = em * s4.x, ay = em * s4.y, az = em * s4.z, aw = em * s4.w;
  int c = 0;
  for (; c + 8 <= k; c += 8) {
    float cf[8]; int dd[8]; ushort4 vv[8];
#pragma unroll
    for (int u = 0; u < 8; ++u) { cf[u] = sv[team][c + u]; dd[u] = sd[team][c + u]; }
#pragma unroll
    for (int u = 0; u < 8; ++u) vv[u] = V4[(size_t)dd[u] * 32 + lane];
#pragma unroll
    for (int u = 0; u < 8; ++u) {
      ax += cf[u] * bf2f(vv[u].x);
      ay += cf[u] * bf2f(vv[u].y);
      az += cf[u] * bf2f(vv[u].z);
      aw += cf[u] * bf2f(vv[u].w);
    }
  }
  for (; c < k; ++c) {
    float cf = sv[team][c];
    ushort4 v0 = V4[(size_t)sd[team][c] * 32 + lane];
    ax += cf * bf2f(v0.x); ay += cf * bf2f(v0.y);
    az += cf * bf2f(v0.z); aw += cf * bf2f(v0.w);
  }
  float4 xx = *(const float4*)&x[(size_t)i * H + lane * 4];
  float4 out;
  out.x = xx.x + ax * Zi; out.y = xx.y + ay * Zi;
  out.z = xx.z + az * Zi; out.w = xx.w + aw * Zi;
  *(float4*)&h1[(size_t)i * H + lane * 4] = out;

  int c0 = lane * 4;
  atomicAdd(&csum[c0 + 0], out.x); atomicAdd(&csq[c0 + 0], out.x * out.x);
  atomicAdd(&csum[c0 + 1], out.y); atomicAdd(&csq[c0 + 1], out.y * out.y);
  atomicAdd(&csum[c0 + 2], out.z); atomicAdd(&csq[c0 + 2], out.z * out.z);
  atomicAdd(&csum[c0 + 3], out.w); atomicAdd(&csq[c0 + 3], out.w * out.w);
  __syncthreads();
  if (tid < H) {
    int bank = blockIdx.x & 15;
    atomicAdd(&sum1p[bank * H + tid], csum[tid]);
    atomicAdd(&sq1p[bank * H + tid], csq[tid]);
  }
}

// ---------------------------------------------------------------------------
// Fused FFN (banked-stats): folds sum1p/sq1p in prologue; t1 tile in LDS only;
// writes BN2 partial sums to 16 banks.
// ---------------------------------------------------------------------------
__global__ __launch_bounds__(256) void ffn_fused(
    const float* __restrict__ h1, const short* __restrict__ W1h,
    const float* __restrict__ b1, const short* __restrict__ W2h,
    const float* __restrict__ b2,
    const float* __restrict__ sum1p, const float* __restrict__ sq1p,
    const float* __restrict__ g1, const float* __restrict__ bb1,
    float* __restrict__ h2, float* __restrict__ sum2p, float* __restrict__ sq2p,
    float invN)
{
  __shared__ __align__(16) short As[32 * LDA];
  __shared__ __align__(16) short Ts[32 * LDA2];
  __shared__ float aF[H], bF[H];
  int tid = threadIdx.x;
  int bm = blockIdx.x * 32;
  int wave = tid >> 6, lane = tid & 63;
  int quad = lane >> 4, l16 = lane & 15;

  if (tid < H) {
    float s = 0.f, q = 0.f;
#pragma unroll
    for (int b = 0; b < 16; ++b) { s += sum1p[b * H + tid]; q += sq1p[b * H + tid]; }
    float mu = s * invN;
    float var = q * invN - mu * mu;
    float rs = rsqrtf(var + EPS);
    float a = g1[tid] * rs;
    aF[tid] = a;
    bF[tid] = bb1[tid] - a * mu;
  }
  __syncthreads();

  int f = tid & 15;
#pragma unroll
  for (int i = 0; i < 2; ++i) {
    int g = i * 256 + tid;
    int row = g >> 4;
    const float4* xp = (const float4*)&h1[(size_t)(bm + row) * H + f * 8];
    float4 v0 = xp[0], v1 = xp[1];
    float vv[8] = {v0.x, v0.y, v0.z, v0.w, v1.x, v1.y, v1.z, v1.w};
    s16x8 hv;
#pragma unroll
    for (int j = 0; j < 8; ++j) {
      int c = f * 8 + j;
      hv[j] = (short)f2bf(aF[c] * vv[j] + bF[c]);
    }
    *(s16x8*)&As[row * LDA + f * 8] = hv;
  }

  int wn1 = wave * 64;
  s16x8 b1f[4][4];
#pragma unroll
  for (int nt = 0; nt < 4; ++nt)
#pragma unroll
    for (int ks = 0; ks < 4; ++ks)
      b1f[nt][ks] = *(const s16x8*)&W1h[(size_t)(wn1 + nt * 16 + l16) * H + ks * 32 + quad * 8];
  __syncthreads();

  f32x4 acc1[2][4];
#pragma unroll
  for (int mt = 0; mt < 2; ++mt)
#pragma unroll
    for (int nt = 0; nt < 4; ++nt) acc1[mt][nt] = (f32x4){0.f, 0.f, 0.f, 0.f};

#pragma unroll
  for (int ks = 0; ks < 4; ++ks) {
    int kof = ks * 32 + quad * 8;
    s16x8 ah[2];
#pragma unroll
    for (int mt = 0; mt < 2; ++mt) ah[mt] = *(s16x8*)&As[(mt * 16 + l16) * LDA + kof];
#pragma unroll
    for (int mt = 0; mt < 2; ++mt)
#pragma unroll
      for (int nt = 0; nt < 4; ++nt)
        acc1[mt][nt] = __builtin_amdgcn_mfma_f32_16x16x32_bf16(ah[mt], b1f[nt][ks], acc1[mt][nt], 0, 0, 0);
  }

#pragma unroll
  for (int nt = 0; nt < 4; ++nt) {
    int col = wn1 + nt * 16 + l16;
    float bb = b1[col];
#pragma unroll
    for (int mt = 0; mt < 2; ++mt)
#pragma unroll
      for (int r = 0; r < 4; ++r) {
        int row = mt * 16 + quad * 4 + r;
        float v = acc1[mt][nt][r] + bb;
        v = v > 0.f ? v : 0.f;
        Ts[row * LDA2 + col] = (short)f2bf(v);
      }
  }

  int wn2 = wave * 32;
  s16x8 b2f[2][8];
#pragma unroll
  for (int nt = 0; nt < 2; ++nt)
#pragma unroll
    for (int ks = 0; ks < 8; ++ks)
      b2f[nt][ks] = *(const s16x8*)&W2h[(size_t)(wn2 + nt * 16 + l16) * H2 + ks * 32 + quad * 8];
  __syncthreads();

  f32x4 acc2[2][2];
#pragma unroll
  for (int mt = 0; mt < 2; ++mt)
#pragma unroll
    for (int nt = 0; nt < 2; ++nt) acc2[mt][nt] = (f32x4){0.f, 0.f, 0.f, 0.f};

#pragma unroll
  for (int ks = 0; ks < 8; ++ks) {
    int kof = ks * 32 + quad * 8;
    s16x8 ah[2];
#pragma unroll
    for (int mt = 0; mt < 2; ++mt) ah[mt] = *(s16x8*)&Ts[(mt * 16 + l16) * LDA2 + kof];
#pragma unroll
    for (int mt = 0; mt < 2; ++mt)
#pragma unroll
      for (int nt = 0; nt < 2; ++nt)
        acc2[mt][nt] = __builtin_amdgcn_mfma_f32_16x16x32_bf16(ah[mt], b2f[nt][ks], acc2[mt][nt], 0, 0, 0);
  }

  int bank = blockIdx.x & 15;
#pragma unroll
  for (int nt = 0; nt < 2; ++nt) {
    int col = wn2 + nt * 16 + l16;
    float ra = aF[col], rb = bF[col];
    float bb = b2[col];
    float ps = 0.f, pq = 0.f;
#pragma unroll
    for (int mt = 0; mt < 2; ++mt)
#pragma unroll
      for (int r = 0; r < 4; ++r) {
        int row = bm + mt * 16 + quad * 4 + r;
        float rr = ra * h1[(size_t)row * H + col] + rb;
        float v = acc2[mt][nt][r] + bb + rr;
        h2[(size_t)row * H + col] = v;
        ps += v; pq += v * v;
      }
    ps += __shfl_xor(ps, 16); ps += __shfl_xor(ps, 32);
    pq += __shfl_xor(pq, 16); pq += __shfl_xor(pq, 32);
    if (quad == 0) {
      atomicAdd(&sum2p[bank * H + col], ps);
      atomicAdd(&sq2p[bank * H + col], pq);
    }
  }
}

// BN2: fold 16 banks -> affine in LDS, then vectorized apply.
__global__ __launch_bounds__(256) void bn_apply(
    const float* __restrict__ X,
    const float* __restrict__ sum2p, const float* __restrict__ sq2p,
    const float* __restrict__ g2, const float* __restrict__ bb2,
    float* __restrict__ Y, size_t n4, float invN)
{
  __shared__ float A2s[H], B2s[H];
  int tid = threadIdx.x;
  if (tid < H) {
    float s = 0.f, q = 0.f;
#pragma unroll
    for (int b = 0; b < 16; ++b) { s += sum2p[b * H + tid]; q += sq2p[b * H + tid]; }
    float mu = s * invN;
    float var = q * invN - mu * mu;
    float rs = rsqrtf(var + EPS);
    float a = g2[tid] * rs;
    A2s[tid] = a;
    B2s[tid] = bb2[tid] - a * mu;
  }
  __syncthreads();
  size_t i = (size_t)blockIdx.x * blockDim.x + tid;
  if (i >= n4) return;
  float4 v = ((const float4*)X)[i];
  int c = (int)((i * 4) & (H - 1));
  float4 a = *(const float4*)&A2s[c];
  float4 b = *(const float4*)&B2s[c];
  v.x = a.x * v.x + b.x; v.y = a.y * v.y + b.y;
  v.z = a.z * v.z + b.z; v.w = a.w * v.w + b.w;
  ((float4*)Y)[i] = v;
}

// ---------------------------------------------------------------------------
extern "C" void kernel_launch(void* const* d_in, const int* in_sizes, int n_in,
                              void* d_out, int out_size, void* d_ws, size_t ws_size,
                              hipStream_t stream)
{
  const float* x  = (const float*)d_in[0];
  const int*   ei = (const int*)d_in[1];
  const float* ea = (const float*)d_in[2];
  const float* Wq = (const float*)d_in[3];
  const float* bq = (const float*)d_in[4];
  const float* Wk = (const float*)d_in[5];
  const float* bk = (const float*)d_in[6];
  const float* Wv = (const float*)d_in[7];
  const float* bv = (const float*)d_in[8];
  const float* We = (const float*)d_in[9];
  const float* be = (const float*)d_in[10];
  const float* g1 = (const float*)d_in[11];
  const float* bb1 = (const float*)d_in[12];
  const float* W1 = (const float*)d_in[13];
  const float* b1 = (const float*)d_in[14];
  const float* W2 = (const float*)d_in[15];
  const float* b2 = (const float*)d_in[16];
  const float* g2 = (const float*)d_in[17];
  const float* bb2 = (const float*)d_in[18];

  int N = in_sizes[0] / H;      // 16384
  int E = in_sizes[2] / 16;     // 524288
  size_t NH = (size_t)N * H;
  float invN = 1.0f / (float)N;

  float* Q   = (float*)d_ws;                         // 8 MB
  float* KmSlot = Q + NH;                            // 8 MB (Kbf + later h2)
  float* h1  = KmSlot + NH;                          // 8 MB
  unsigned short* Vbf = (unsigned short*)(h1 + NH);  // 4 MB
  int2*  slabDE = (int2*)(Vbf + NH);                 // 12 MB
  int*   cnt    = (int*)(slabDE + (size_t)N * SLAB);
  float* stats  = (float*)(cnt + N);
  float* SVp   = stats;
  float* sum1p = stats + 8 * H;
  float* sq1p  = sum1p + 16 * H;
  float* sum2p = sq1p + 16 * H;
  float* sq2p  = sum2p + 16 * H;
  float* statsEnd = sq2p + 16 * H;      // 72*H floats total
  short* wbuf = (short*)statsEnd;
  short* Wqh = wbuf;
  short* Wql = Wqh + 16384;
  short* Wkh = Wql + 16384;
  short* Wkl = Wkh + 16384;
  short* Wvh = Wkl + 16384;
  short* W1h = Wvh + 16384;
  short* W2h = W1h + 32768;
  unsigned short* Kbf = (unsigned short*)KmSlot;  // 4 MB, dead after attn_fused
  float* h2 = KmSlot;                             // alias (Kbf dead after attn)

  // wprep jobs 0-4: weight transpose/convert; job 5: zero cnt + stats
  wprep<<<dim3(128, 1, 6), 256, 0, stream>>>(Wq, Wk, Wv, W1, W2,
      Wqh, Wql, Wkh, Wkl, Wvh, W1h, W2h, cnt, stats, N);

  qkv_mfma<<<dim3(N / 64), 256, 0, stream>>>(
      x, Wqh, Wql, Wkh, Wkl, Wvh, bq, bk, bv, Q, Kbf, Vbf, SVp);

  ebfill<<<dim3(2048), 256, 0, stream>>>(ea, We, be, ei, cnt, slabDE, E, N);

  attn_fused<<<dim3(N / 8), 256, 0, stream>>>(x, Q, Kbf, Vbf, SVp, cnt, slabDE,
                                              h1, sum1p, sq1p, N);

  ffn_fused<<<dim3(N / 32), 256, 0, stream>>>(h1, W1h, b1, W2h, b2,
      sum1p, sq1p, g1, bb1, h2, sum2p, sq2p, invN);

  bn_apply<<<dim3((int)((NH / 4 + 255) / 256)), 256, 0, stream>>>(
      h2, sum2p, sq2p, g2, bb2, (float*)d_out, NH / 4, invN);
}